// Round 2
// baseline (30.619 us; speedup 1.0000x reference)
//
#include <hip/hip_runtime.h>
#include <math.h>

// Solve (A * diag(dm)) x = f where A = kron(I,T)+kron(T,I), T = tridiag(-1,2,-1), N=80.
// => x = (A^{-1} f) ./ dm, with A^{-1} applied exactly via the 2D DST-I fast
// Poisson solver: Y = (2/81)^2 * S[(S F S) ./ (lam_a+lam_b)]S,
// S[k][i] = sin(pi (k+1)(i+1)/81), lam_k = 4 sin^2(pi (k+1)/162).
// dm(i,j) = 1 + sum_k amps[k] exp(-((x_i-cx_k)^2 + (y_j-cy_k)^2)), x_i = -1 + 2i/79.
// The 6400x6400 dense A input is structurally known and never read.

#define NN   80
#define NP   81
#define PAD  84     // row stride in floats: 336B = multiple of 16B; spreads banks
#define NTH  1024

__device__ __forceinline__ void gemm2x4(const float (*__restrict__ Lb)[PAD],
                                        const float (*__restrict__ Rb)[PAD],
                                        int r0, int c4, float acc[2][4])
{
    float a00=0,a01=0,a02=0,a03=0,a10=0,a11=0,a12=0,a13=0;
    #pragma unroll 8
    for (int k = 0; k < NN; ++k) {
        const float4 rv = *reinterpret_cast<const float4*>(&Rb[k][c4]);
        const float l0 = Lb[r0][k];
        const float l1 = Lb[r0 + 1][k];
        a00 += l0*rv.x; a01 += l0*rv.y; a02 += l0*rv.z; a03 += l0*rv.w;
        a10 += l1*rv.x; a11 += l1*rv.y; a12 += l1*rv.z; a13 += l1*rv.w;
    }
    acc[0][0]=a00; acc[0][1]=a01; acc[0][2]=a02; acc[0][3]=a03;
    acc[1][0]=a10; acc[1][1]=a11; acc[1][2]=a12; acc[1][3]=a13;
}

__global__ __launch_bounds__(NTH) void poisson_dst_kernel(
    const float* __restrict__ alpha,
    const float* __restrict__ f,
    float* __restrict__ out)
{
    __shared__ __align__(16) float Sm[NN][PAD];   // sine matrix (symmetric)
    __shared__ __align__(16) float Ab[NN][PAD];   // work buffer A
    __shared__ __align__(16) float Bb[NN][PAD];   // work buffer B
    __shared__ float lam[NN];
    __shared__ float al[12];

    const int tid = threadIdx.x;

    if (tid < 12) al[tid] = alpha[tid];
    // Build S and load f. Reduce sin argument via periodicity (period 162 in (k+1)(i+1))
    for (int p = tid; p < NN * NN; p += NTH) {
        const int k = p / NN, i = p - k * NN;
        const int m = ((k + 1) * (i + 1)) % (2 * NP);
        Sm[k][i] = sinf(3.14159265358979323846f * (float)m / (float)NP);
        Ab[k][i] = f[p];
    }
    if (tid < NN) {
        const float s = sinf(3.14159265358979323846f * (float)(tid + 1) / (2.0f * (float)NP));
        lam[tid] = 4.0f * s * s;
    }
    __syncthreads();

    // Each active thread owns a 2x4 output tile per stage: rows r0,r0+1, cols c4..c4+3
    const bool active = tid < (NN / 2) * (NN / 4);   // 40*20 = 800
    const int r0 = (tid / 20) * 2;
    const int c4 = (tid % 20) * 4;

    float acc[2][4];

    // Stage 1: Bb = S * F          (F in Ab)
    if (active) {
        gemm2x4(Sm, Ab, r0, c4, acc);
        *reinterpret_cast<float4*>(&Bb[r0][c4])   = make_float4(acc[0][0],acc[0][1],acc[0][2],acc[0][3]);
        *reinterpret_cast<float4*>(&Bb[r0+1][c4]) = make_float4(acc[1][0],acc[1][1],acc[1][2],acc[1][3]);
    }
    __syncthreads();

    // Stage 2: Ab = (Bb * S) ./ (lam_r + lam_c)
    if (active) {
        gemm2x4(Bb, Sm, r0, c4, acc);
        const float lr0 = lam[r0], lr1 = lam[r0 + 1];
        const float l0 = lam[c4+0], l1 = lam[c4+1], l2 = lam[c4+2], l3 = lam[c4+3];
        *reinterpret_cast<float4*>(&Ab[r0][c4]) =
            make_float4(acc[0][0]/(lr0+l0), acc[0][1]/(lr0+l1), acc[0][2]/(lr0+l2), acc[0][3]/(lr0+l3));
        *reinterpret_cast<float4*>(&Ab[r0+1][c4]) =
            make_float4(acc[1][0]/(lr1+l0), acc[1][1]/(lr1+l1), acc[1][2]/(lr1+l2), acc[1][3]/(lr1+l3));
    }
    __syncthreads();

    // Stage 3: Bb = S * Ab
    if (active) {
        gemm2x4(Sm, Ab, r0, c4, acc);
        *reinterpret_cast<float4*>(&Bb[r0][c4])   = make_float4(acc[0][0],acc[0][1],acc[0][2],acc[0][3]);
        *reinterpret_cast<float4*>(&Bb[r0+1][c4]) = make_float4(acc[1][0],acc[1][1],acc[1][2],acc[1][3]);
    }
    __syncthreads();

    // Stage 4: Y = (Bb * S) * (2/81)^2 ; out = Y ./ dm  (written straight to global)
    if (active) {
        gemm2x4(Bb, Sm, r0, c4, acc);
        const float scale = 4.0f / ((float)NP * (float)NP);
        #pragma unroll
        for (int rr = 0; rr < 2; ++rr) {
            const int i = r0 + rr;
            const float xi = -1.0f + 2.0f * (float)i / 79.0f;
            #pragma unroll
            for (int cc = 0; cc < 4; ++cc) {
                const int j = c4 + cc;
                const float yj = -1.0f + 2.0f * (float)j / 79.0f;
                float dm = 1.0f;
                #pragma unroll
                for (int kk = 0; kk < 4; ++kk) {
                    const float dx = xi - al[4 + kk];
                    const float dy = yj - al[8 + kk];
                    dm += al[kk] * expf(-(dx*dx + dy*dy));
                }
                out[i * NN + j] = acc[rr][cc] * scale / dm;
            }
        }
    }
}

extern "C" void kernel_launch(void* const* d_in, const int* in_sizes, int n_in,
                              void* d_out, int out_size, void* d_ws, size_t ws_size,
                              hipStream_t stream) {
    const float* alpha = (const float*)d_in[0];   // 16 floats: amps, cx, cy, (unused)
    // d_in[1] is A (6400x6400) — structurally known, never read.
    const float* f = (const float*)d_in[2];       // 6400 floats
    float* out = (float*)d_out;                   // 6400 floats

    hipLaunchKernelGGL(poisson_dst_kernel, dim3(1), dim3(NTH), 0, stream,
                       alpha, f, out);
}

// Round 4
// 28.785 us; speedup vs baseline: 1.0637x; 1.0637x over previous
//
#include <hip/hip_runtime.h>
#include <math.h>

// Solve (A * diag(dm)) x = f where A = kron(I,T)+kron(T,I), T = tridiag(-1,2,-1), N=80.
// => x = (A^{-1} f) ./ dm, with A^{-1} applied exactly via the 2D DST-I fast
// Poisson solver: Y = (2/81)^2 * S[(S F S) ./ (lam_a+lam_b)]S,
// S[k][i] = sin(pi (k+1)(i+1)/81), lam_k = 4 sin^2(pi (k+1)/162).
// dm(i,j) = 1 + sum_k amps[k] exp(-(x_i-cx_k)^2) * exp(-(y_j-cy_k)^2)  (separable).
// The 6400x6400 dense A input is structurally known and never read.
//
// Perf model: single-CU, LDS-read-throughput bound. 4x8 register tiles ->
// 750 ds_read_b128 per stage (vs 1560 at 2x4), ~12cyc each, 4 stages ~ 15us.

#define NN   80
#define NP   81
#define PAD  84     // row stride: 336B = multiple of 16B; spreads banks
#define NTH  512    // 8 waves: setup parallelism; 200 threads active in GEMM

__device__ __forceinline__ void gemm4x8(const float (*__restrict__ Lb)[PAD],
                                        const float (*__restrict__ Rb)[PAD],
                                        int r0, int c8, float acc[4][8])
{
    #pragma unroll
    for (int r = 0; r < 4; ++r)
        #pragma unroll
        for (int c = 0; c < 8; ++c)
            acc[r][c] = 0.0f;

    #pragma unroll 8
    for (int k = 0; k < NN; ++k) {
        const float4 rv0 = *reinterpret_cast<const float4*>(&Rb[k][c8]);
        const float4 rv1 = *reinterpret_cast<const float4*>(&Rb[k][c8 + 4]);
        #pragma unroll
        for (int r = 0; r < 4; ++r) {
            const float l = Lb[r0 + r][k];
            acc[r][0] += l * rv0.x; acc[r][1] += l * rv0.y;
            acc[r][2] += l * rv0.z; acc[r][3] += l * rv0.w;
            acc[r][4] += l * rv1.x; acc[r][5] += l * rv1.y;
            acc[r][6] += l * rv1.z; acc[r][7] += l * rv1.w;
        }
    }
}

__global__ __launch_bounds__(NTH) void poisson_dst_kernel(
    const float* __restrict__ alpha,
    const float* __restrict__ f,
    float* __restrict__ out)
{
    __shared__ __align__(16) float Sm[NN][PAD];   // sine matrix (symmetric)
    __shared__ __align__(16) float Ab[NN][PAD];   // work buffer A
    __shared__ __align__(16) float Bb[NN][PAD];   // work buffer B
    __shared__ float lam[NN];
    __shared__ float gx[4][NN];   // amps_k * exp(-(x_i-cx_k)^2)
    __shared__ float gy[4][NN];   // exp(-(y_j-cy_k)^2)

    const int tid = threadIdx.x;
    const float PI = 3.14159265358979323846f;

    // Build S and load f. Reduce sin argument via periodicity (period 162 in (k+1)(i+1))
    for (int p = tid; p < NN * NN; p += NTH) {
        const int k = p / NN, i = p - k * NN;
        const int m = ((k + 1) * (i + 1)) % (2 * NP);
        Sm[k][i] = sinf(PI * (float)m / (float)NP);
        Ab[k][i] = f[p];
    }
    if (tid < NN) {
        const float s = sinf(PI * (float)(tid + 1) / (2.0f * (float)NP));
        lam[tid] = 4.0f * s * s;
    }
    // Separable Gaussian tables: one thread per (k,i) does BOTH gx and gy
    // (320 threads — must stay < NTH; the R3 bug was a 640-wide guard at NTH=512).
    if (tid < 4 * NN) {
        const int k = tid / NN;
        const int i = tid % NN;
        const float xi = -1.0f + 2.0f * (float)i / 79.0f;
        const float dx = xi - alpha[4 + k];
        const float dy = xi - alpha[8 + k];
        gx[k][i] = alpha[k] * __expf(-(dx * dx));
        gy[k][i] = __expf(-(dy * dy));
    }
    __syncthreads();

    // 4x8 output tiles: 20 row-groups x 10 col-groups = 200 active threads
    const bool active = tid < 200;
    const int r0 = (tid / 10) * 4;
    const int c8 = (tid % 10) * 8;

    float acc[4][8];

    // Stage 1: Bb = S * F          (F in Ab)
    if (active) {
        gemm4x8(Sm, Ab, r0, c8, acc);
        #pragma unroll
        for (int r = 0; r < 4; ++r) {
            *reinterpret_cast<float4*>(&Bb[r0 + r][c8]) =
                make_float4(acc[r][0], acc[r][1], acc[r][2], acc[r][3]);
            *reinterpret_cast<float4*>(&Bb[r0 + r][c8 + 4]) =
                make_float4(acc[r][4], acc[r][5], acc[r][6], acc[r][7]);
        }
    }
    __syncthreads();

    // Stage 2: Ab = (Bb * S) ./ (lam_r + lam_c)
    if (active) {
        gemm4x8(Bb, Sm, r0, c8, acc);
        float lc[8];
        #pragma unroll
        for (int c = 0; c < 8; ++c) lc[c] = lam[c8 + c];
        #pragma unroll
        for (int r = 0; r < 4; ++r) {
            const float lr = lam[r0 + r];
            #pragma unroll
            for (int c = 0; c < 8; ++c) acc[r][c] /= (lr + lc[c]);
            *reinterpret_cast<float4*>(&Ab[r0 + r][c8]) =
                make_float4(acc[r][0], acc[r][1], acc[r][2], acc[r][3]);
            *reinterpret_cast<float4*>(&Ab[r0 + r][c8 + 4]) =
                make_float4(acc[r][4], acc[r][5], acc[r][6], acc[r][7]);
        }
    }
    __syncthreads();

    // Stage 3: Bb = S * Ab
    if (active) {
        gemm4x8(Sm, Ab, r0, c8, acc);
        #pragma unroll
        for (int r = 0; r < 4; ++r) {
            *reinterpret_cast<float4*>(&Bb[r0 + r][c8]) =
                make_float4(acc[r][0], acc[r][1], acc[r][2], acc[r][3]);
            *reinterpret_cast<float4*>(&Bb[r0 + r][c8 + 4]) =
                make_float4(acc[r][4], acc[r][5], acc[r][6], acc[r][7]);
        }
    }
    __syncthreads();

    // Stage 4: Y = (Bb * S) * (2/81)^2 ; out = Y ./ dm  (written straight to global)
    if (active) {
        gemm4x8(Bb, Sm, r0, c8, acc);
        const float scale = 4.0f / ((float)NP * (float)NP);
        float gyv[4][8];
        #pragma unroll
        for (int k = 0; k < 4; ++k)
            #pragma unroll
            for (int c = 0; c < 8; ++c) gyv[k][c] = gy[k][c8 + c];
        #pragma unroll
        for (int r = 0; r < 4; ++r) {
            const int i = r0 + r;
            float gxr[4];
            #pragma unroll
            for (int k = 0; k < 4; ++k) gxr[k] = gx[k][i];
            #pragma unroll
            for (int c = 0; c < 8; ++c) {
                float dm = 1.0f;
                #pragma unroll
                for (int k = 0; k < 4; ++k) dm += gxr[k] * gyv[k][c];
                out[i * NN + c8 + c] = acc[r][c] * scale / dm;
            }
        }
    }
}

extern "C" void kernel_launch(void* const* d_in, const int* in_sizes, int n_in,
                              void* d_out, int out_size, void* d_ws, size_t ws_size,
                              hipStream_t stream) {
    const float* alpha = (const float*)d_in[0];   // 16 floats: amps, cx, cy, (unused)
    // d_in[1] is A (6400x6400) — structurally known, never read.
    const float* f = (const float*)d_in[2];       // 6400 floats
    float* out = (float*)d_out;                   // 6400 floats

    hipLaunchKernelGGL(poisson_dst_kernel, dim3(1), dim3(NTH), 0, stream,
                       alpha, f, out);
}

// Round 5
// 16.063 us; speedup vs baseline: 1.9061x; 1.7920x over previous
//
#include <hip/hip_runtime.h>
#include <math.h>

// Solve (A * diag(dm)) x = f, A = kron(I,T)+kron(T,I), T = tridiag(-1,2,-1), N=80.
// x = (A^{-1} f) ./ dm via DST-I fast Poisson solver, split at the one true
// data dependency into two multi-CU kernels:
//   K1: U2 = (S·F·S) ./ (lam_a + lam_b)      (row-blocks independent)
//   K2: out = (2/81)^2 · (S·U2·S) ./ dm      (row-blocks independent given U2)
// S[k][i] = sin(pi(k+1)(i+1)/81) (symmetric), lam_k = 4 sin^2(pi(k+1)/162),
// dm(i,j) = 1 + sum_k amps_k exp(-(x_i-cx_k)^2) exp(-(y_j-cy_k)^2)  (separable).
// The 6400x6400 dense A input is structurally known and never read.

#define NN   80
#define NP   81
#define RPW  4                 // output rows per workgroup
#define NWG  (NN / RPW)        // 20 workgroups
#define NTH  (RPW * NN)        // 320 threads = 5 waves; thread <-> (row, col) 1:1
#define PIF  3.14159265358979323846f

// Build the 162-entry sine table: S values only take sin(pi*m/81), m in [0,162).
__device__ __forceinline__ void build_sin_table(float* tbl, int tid) {
    if (tid < 2 * NP) tbl[tid] = sinf(PIF * (float)tid / (float)NP);
}

__device__ __forceinline__ void build_S(float (*Sm)[NN], const float* tbl, int tid) {
    for (int p = tid; p < NN * NN; p += NTH) {
        const int k = p / NN, i = p - k * NN;
        Sm[k][i] = tbl[((k + 1) * (i + 1)) % (2 * NP)];
    }
}

// ---------------- K1: U2 = (S F S) ./ (lam_r + lam_c) ----------------
__global__ __launch_bounds__(NTH) void poisson_phase1(
    const float* __restrict__ f, float* __restrict__ u2g)
{
    __shared__ __align__(16) float Sm[NN][NN];
    __shared__ __align__(16) float Fl[NN][NN];
    __shared__ float U1[RPW][NN];
    __shared__ float tbl[2 * NP];
    __shared__ float lam[NN];

    const int tid = threadIdx.x;
    const int wg  = blockIdx.x;

    build_sin_table(tbl, tid);
    if (tid < NN) {
        const float s = sinf(PIF * (float)(tid + 1) / (2.0f * (float)NP));
        lam[tid] = 4.0f * s * s;
    }
    for (int p = tid; p < NN * NN / 4; p += NTH)
        reinterpret_cast<float4*>(&Fl[0][0])[p] =
            reinterpret_cast<const float4*>(f)[p];
    __syncthreads();                    // tbl ready
    build_S(Sm, tbl, tid);
    __syncthreads();                    // Sm, Fl, lam ready

    const int r = tid / NN;             // 0..3
    const int i = tid - r * NN;         // 0..79
    const int a = wg * RPW + r;         // owned row of U1/U2

    // U1[a][i] = sum_k S[a][k] * F[k][i]   (S[a][k]: LDS broadcast; F[k][i]: stride-1)
    float acc = 0.0f;
    #pragma unroll 8
    for (int k = 0; k < NN; ++k) acc += Sm[a][k] * Fl[k][i];
    U1[r][i] = acc;
    __syncthreads();                    // row of U1 complete

    // U2[a][i] = (sum_k U1[a][k] * S[k][i]) / (lam_a + lam_i)
    float acc2 = 0.0f;
    #pragma unroll 8
    for (int k = 0; k < NN; ++k) acc2 += U1[r][k] * Sm[k][i];
    u2g[a * NN + i] = acc2 / (lam[a] + lam[i]);
}

// ---------------- K2: out = scale * (S U2 S) ./ dm ----------------
__global__ __launch_bounds__(NTH) void poisson_phase2(
    const float* __restrict__ alpha, const float* __restrict__ u2g,
    float* __restrict__ out)
{
    __shared__ __align__(16) float Sm[NN][NN];
    __shared__ __align__(16) float U2[NN][NN];
    __shared__ float Tl[RPW][NN];
    __shared__ float tbl[2 * NP];
    __shared__ float gyl[4][NN];        // exp(-(y_j - cy_k)^2)
    __shared__ float gxv[RPW][4];       // amps_k * exp(-(x_row - cx_k)^2)

    const int tid = threadIdx.x;
    const int wg  = blockIdx.x;

    build_sin_table(tbl, tid);
    for (int p = tid; p < NN * NN / 4; p += NTH)
        reinterpret_cast<float4*>(&U2[0][0])[p] =
            reinterpret_cast<const float4*>(u2g)[p];
    {   // all 320 threads: one gy entry each (k = tid/80 in 0..3)
        const int k = tid / NN, j = tid - k * NN;
        const float yj = -1.0f + 2.0f * (float)j / 79.0f;
        const float d  = yj - alpha[8 + k];
        gyl[k][j] = __expf(-(d * d));
    }
    if (tid < RPW * 4) {
        const int r = tid / 4, k = tid - r * 4;
        const float xi = -1.0f + 2.0f * (float)(wg * RPW + r) / 79.0f;
        const float d  = xi - alpha[4 + k];
        gxv[r][k] = alpha[k] * __expf(-(d * d));
    }
    __syncthreads();                    // tbl ready
    build_S(Sm, tbl, tid);
    __syncthreads();                    // Sm, U2, gy, gx ready

    const int r   = tid / NN;
    const int j   = tid - r * NN;
    const int row = wg * RPW + r;

    // T[row][j] = sum_a S[row][a] * U2[a][j]
    float t = 0.0f;
    #pragma unroll 8
    for (int a = 0; a < NN; ++a) t += Sm[row][a] * U2[a][j];
    Tl[r][j] = t;
    __syncthreads();

    // Y[row][j] = sum_b T[row][b] * S[b][j];  out = Y * scale / dm
    float y = 0.0f;
    #pragma unroll 8
    for (int b = 0; b < NN; ++b) y += Tl[r][b] * Sm[b][j];

    float dm = 1.0f;
    #pragma unroll
    for (int k = 0; k < 4; ++k) dm += gxv[r][k] * gyl[k][j];

    const float scale = 4.0f / ((float)NP * (float)NP);
    out[row * NN + j] = y * scale / dm;
}

extern "C" void kernel_launch(void* const* d_in, const int* in_sizes, int n_in,
                              void* d_out, int out_size, void* d_ws, size_t ws_size,
                              hipStream_t stream) {
    const float* alpha = (const float*)d_in[0];   // 16 floats: amps, cx, cy, (unused)
    // d_in[1] is A (6400x6400) — structurally known, never read.
    const float* f = (const float*)d_in[2];       // 6400 floats
    float* out = (float*)d_out;                   // 6400 floats
    float* u2  = (float*)d_ws;                    // 6400 floats scratch (25.6 KB)

    hipLaunchKernelGGL(poisson_phase1, dim3(NWG), dim3(NTH), 0, stream, f, u2);
    hipLaunchKernelGGL(poisson_phase2, dim3(NWG), dim3(NTH), 0, stream, alpha, u2, out);
}